// Round 10
// baseline (214.978 us; speedup 1.0000x reference)
//
#include <hip/hip_runtime.h>

#define NLAYER 7
#define IMGB 16384          // bytes per weight-layer image: A[n][k] fp8, plain row-major
#define WSCALE 16.0f        // weights stored x16 (e4m3 subnormal protection)

typedef __attribute__((ext_vector_type(2))) float float2v;
typedef __attribute__((ext_vector_type(4))) float float4v;
typedef __attribute__((ext_vector_type(2))) int   int2v;
typedef __attribute__((ext_vector_type(4))) int   int4v;
typedef __attribute__((ext_vector_type(4))) unsigned int uint4v;
typedef __attribute__((ext_vector_type(8))) int   int8v;
typedef unsigned long long u64;

// ---- forced VOP3P packed-f32 (compiler doesn't form these on its own) ----
__device__ __forceinline__ float2v pk_fma(float2v a, float2v b, float2v c){
  float2v d;
  asm("v_pk_fma_f32 %0, %1, %2, %3" : "=v"(d) : "v"(a), "v"(b), "v"(c));
  return d;
}
__device__ __forceinline__ float2v pk_mul(float2v a, float2v b){
  float2v d;
  asm("v_pk_mul_f32 %0, %1, %2" : "=v"(d) : "v"(a), "v"(b));
  return d;
}
__device__ __forceinline__ float2v pk_add(float2v a, float2v b){
  float2v d;
  asm("v_pk_add_f32 %0, %1, %2" : "=v"(d) : "v"(a), "v"(b));
  return d;
}
__device__ __forceinline__ float2v lo2(float4v v){ return (float2v){v[0], v[1]}; }
__device__ __forceinline__ float2v hi2(float4v v){ return (float2v){v[2], v[3]}; }

// pack 4 f32 -> 4 fp8 e4m3 bytes (ascending)
__device__ __forceinline__ unsigned pk4fp8(float v0, float v1, float v2, float v3){
  int w = __builtin_amdgcn_cvt_pk_fp8_f32(v0, v1, 0, false);
  w = __builtin_amdgcn_cvt_pk_fp8_f32(v2, v3, w, true);
  return (unsigned)w;
}
template<bool HI>
__device__ __forceinline__ float2v up2(unsigned w){
  return __builtin_amdgcn_cvt_pk_f32_fp8((int)w, HI);
}
// MX-scaled MFMA, K=128, FMT=fp8 e4m3 both operands, scales = 1.0 (E8M0 0x7F)
__device__ __forceinline__ float4v mfma128(int8v a, int8v b){
  return __builtin_amdgcn_mfma_scale_f32_16x16x128_f8f6f4(
      a, b, (float4v){0.f,0.f,0.f,0.f}, 0, 0, 0, 0x7F7F7F7F, 0, 0x7F7F7F7F);
}
// P16 = 16*Phi(z) (cubic Taylor), gp16 = 16*gelu'(z)  [natural z scale, L0 only]
__device__ __forceinline__ void act2(float2v z, float2v& P16, float2v& gp16){
  const float2v c1v  = {6.3830764862829235f, 6.3830764862829235f};
  const float2v c3v  = {-1.0638460810704874f, -1.0638460810704874f};
  const float2v c33v = {-3.1915382432114624f, -3.1915382432114624f};
  const float2v v8   = {8.f, 8.f};
  float2v z2 = pk_mul(z, z);
  float2v u  = pk_fma(z2, c3v, c1v);
  P16 = pk_fma(z, u, v8);
  float2v Pd = pk_fma(z2, c33v, c1v);
  gp16 = pk_fma(z, Pd, P16);
}

// B operand: 4 swizzled b64 chunks = k-bytes 32q..32q+31 of one element's LDS row
__device__ __forceinline__ int8v ld_b(const unsigned char* row, int q, int m0){
  int2v x0 = *(const int2v*)(row + (((4*q+0) ^ m0)*8));
  int2v x1 = *(const int2v*)(row + (((4*q+1) ^ m0)*8));
  int2v x2 = *(const int2v*)(row + (((4*q+2) ^ m0)*8));
  int2v x3 = *(const int2v*)(row + (((4*q+3) ^ m0)*8));
  int4v lo = __builtin_shufflevector(x0, x1, 0, 1, 2, 3);
  int4v hi = __builtin_shufflevector(x2, x3, 0, 1, 2, 3);
  return __builtin_shufflevector(lo, hi, 0, 1, 2, 3, 4, 5, 6, 7);
}
// A operand: 32 contiguous bytes from the plain global image (2x dwordx4)
__device__ __forceinline__ int8v ld_a(const unsigned char* p){
  int4v a0 = *(const int4v*)(p);
  int4v a1 = *(const int4v*)(p + 16);
  return __builtin_shufflevector(a0, a1, 0, 1, 2, 3, 4, 5, 6, 7);
}

// ---- prep: Wh fp32 [side][term][L][k][n] -> fp8 image [net][L][n][k] (plain), W*16 ----
__global__ __launch_bounds__(256)
void prep_weights(const float* __restrict__ lWh,
                  const float* __restrict__ rWh,
                  unsigned char* __restrict__ wbf)
{
  __shared__ __align__(16) unsigned char T[IMGB];
  const int b = blockIdx.x;               // net*7 + L
  const int net = b / NLAYER, L = b % NLAYER;
  const int side = net >> 1, term = net & 1;
  const float* src = (side ? rWh : lWh) + (size_t)((term*NLAYER + L)*128)*128;
  const int t = threadIdx.x;
  {
    const int k = t >> 1, n0 = (t & 1)*64;
    const float* row = src + k*128 + n0;
    #pragma unroll
    for (int c4 = 0; c4 < 4; ++c4){
      float4v f0 = *(const float4v*)(row + c4*16);
      float4v f1 = *(const float4v*)(row + c4*16 + 4);
      float4v f2 = *(const float4v*)(row + c4*16 + 8);
      float4v f3 = *(const float4v*)(row + c4*16 + 12);
      uint4v wv = { pk4fp8(f0[0]*WSCALE, f0[1]*WSCALE, f0[2]*WSCALE, f0[3]*WSCALE),
                    pk4fp8(f1[0]*WSCALE, f1[1]*WSCALE, f1[2]*WSCALE, f1[3]*WSCALE),
                    pk4fp8(f2[0]*WSCALE, f2[1]*WSCALE, f2[2]*WSCALE, f2[3]*WSCALE),
                    pk4fp8(f3[0]*WSCALE, f3[1]*WSCALE, f3[2]*WSCALE, f3[3]*WSCALE) };
      *(uint4v*)&T[k*128 + n0 + c4*16] = wv;
    }
  }
  __syncthreads();
  {
    const int n = t >> 1, c0 = (t & 1)*8;
    unsigned char* dst = wbf + ((size_t)b << 14) + n*128;
    #pragma unroll
    for (int c = 0; c < 8; ++c){
      const int kc = (c0 + c)*8;
      u64 v = 0;
      #pragma unroll
      for (int j = 0; j < 8; ++j)
        v |= (u64)T[(kc + j)*128 + n] << (8*j);
      *(u64*)(dst + (c0 + c)*8) = v;
    }
  }
}

__global__ __launch_bounds__(256, 4)
void sympl_main(const float* __restrict__ X,
                const float* __restrict__ lW0, const float* __restrict__ lb0,
                const float* __restrict__ lbh, const float* __restrict__ lWo,
                const float* __restrict__ rW0, const float* __restrict__ rb0,
                const float* __restrict__ rbh, const float* __restrict__ rWo,
                const int* __restrict__ lidx, const int* __restrict__ ridx,
                const unsigned char* __restrict__ wbf,
                float* __restrict__ out)
{
  // double-buffered activations; each buf: rows 0-31 S_h, rows 32-63 S_d
  // element row e, byte-chunk c: addr = e*128 + (c ^ (e&15))*8
  __shared__ __align__(16) unsigned char sH[2][8192];

  const int tid  = threadIdx.x;
  const int lane = tid & 63;
  const int w    = tid >> 6;
  const int m0   = lane & 15;
  const int q    = lane >> 4;
  const int col  = blockIdx.y;
  const int e0   = blockIdx.x * 32;
  const int r    = tid >> 3;       // element 0..31 (8 threads each)
  const int sg   = tid & 7;
  const int rs   = r & 15;

  const int lt = (lidx[0] == col) ? 0 : 1;
  const int rt = (ridx[0] == col) ? 0 : 1;

  float qv = X[(e0 + r)*4 + col];
  float pv = X[(e0 + r)*4 + 2 + col];

  const float dt = 0.1f;
  const float C0 = 0.6756035959798289f, C1 = -0.17560359597982883f;
  const float D0 = 1.3512071919596578f, D1 = -1.7024143839193153f;
  // fold 1/(16*4^7) = 1/262144 (final S_d scale) into the step coefficients
  const float is = 1.0f / 262144.0f;
  const float coefs[7] = { C0*dt*is, -D0*dt*is, C1*dt*is, -D1*dt*is,
                           C1*dt*is, -D0*dt*is, C0*dt*is };

  // epilogue constants: polynomials in u = 256*z (R5-verified folded scales)
  const float2v K0 = {0.03125f, 0.03125f};            // Sh = u*(K0 + K1 u + K3 u^3)
  const float2v K1 = {9.739801768e-5f, 9.739801768e-5f};
  const float2v K3 = {-2.476767495e-10f, -2.476767495e-10f};
  const float2v G0 = {0.125f, 0.125f};                // Sd = acc1*(G0 + G1 u + G3 u^3)
  const float2v G1 = {7.791841414e-4f, 7.791841414e-4f};
  const float2v G3 = {-3.962875977e-9f, -3.962875977e-9f};
  const float2v v256p = {256.f, 256.f};

  // per-wave operand offsets (loop-invariant)
  const int aoff0 = ((2*w + 0)*16 + m0)*128 + q*32;
  const int aoff1 = ((2*w + 1)*16 + m0)*128 + q*32;

  // prefetched A-frags + prescaled biases (256*b) for the upcoming hidden layer
  int8v   pa0, pa1;
  float2v pbl0, pbh0, pbl1, pbh1;

  for (int ev = 0; ev < 7; ++ev){
    const bool isT = !(ev & 1);
    const int  term = isT ? rt : lt;
    const float* W0p = (isT ? rW0 : lW0) + term*128;
    const float* b0p = (isT ? rb0 : lb0) + term*128;
    const float* bhp = (isT ? rbh : lbh) + term*NLAYER*128;
    const float* Wop = (isT ? rWo : lWo) + term*128;
    const unsigned char* wimg = wbf + (size_t)(((isT ? 2 : 0) + term)*NLAYER)*IMGB;

    // prefetch L=0 operands (hidden by layer-0 compute + barrier)
    pa0 = ld_a(wimg + aoff0);
    pa1 = ld_a(wimg + aoff1);
    {
      float4v tb0 = *(const float4v*)(bhp + (2*w + 0)*16 + q*4);
      float4v tb1 = *(const float4v*)(bhp + (2*w + 1)*16 + q*4);
      pbl0 = pk_mul(lo2(tb0), v256p); pbh0 = pk_mul(hi2(tb0), v256p);
      pbl1 = pk_mul(lo2(tb1), v256p); pbh1 = pk_mul(hi2(tb1), v256p);
    }

    // ---- layer 0 -> sH[0]: S_h = 16*gelu(z), S_d = 16*gelu'(z)*w, z = x*w+b ----
    {
      const float x = isT ? pv : qv;
      const float2v xv = {x, x};
      unsigned char* pH = sH[0] + r*128;
      unsigned char* pD = pH + 4096;
      #pragma unroll
      for (int c = 0; c < 2; ++c){
        int n0 = sg*16 + c*8;
        float4v wa = *(const float4v*)(W0p + n0);
        float4v wb = *(const float4v*)(W0p + n0 + 4);
        float4v ba = *(const float4v*)(b0p + n0);
        float4v bb = *(const float4v*)(b0p + n0 + 4);
        float2v zp[4] = { pk_fma(xv, lo2(wa), lo2(ba)), pk_fma(xv, hi2(wa), hi2(ba)),
                          pk_fma(xv, lo2(wb), lo2(bb)), pk_fma(xv, hi2(wb), hi2(bb)) };
        float2v wp[4] = { lo2(wa), hi2(wa), lo2(wb), hi2(wb) };
        float Sh[8], Sd[8];
        #pragma unroll
        for (int pp = 0; pp < 4; ++pp){
          float2v P16, gp16; act2(zp[pp], P16, gp16);
          float2v h = pk_mul(zp[pp], P16);
          float2v d = pk_mul(gp16, wp[pp]);
          Sh[pp*2] = h[0]; Sh[pp*2+1] = h[1];
          Sd[pp*2] = d[0]; Sd[pp*2+1] = d[1];
        }
        u64 hv = (u64)pk4fp8(Sh[0],Sh[1],Sh[2],Sh[3]) | ((u64)pk4fp8(Sh[4],Sh[5],Sh[6],Sh[7]) << 32);
        u64 dv = (u64)pk4fp8(Sd[0],Sd[1],Sd[2],Sd[3]) | ((u64)pk4fp8(Sd[4],Sd[5],Sd[6],Sd[7]) << 32);
        int off = ((2*sg + c) ^ rs) * 8;
        *(u64*)(pH + off) = hv;
        *(u64*)(pD + off) = dv;
      }
    }
    __syncthreads();

    // ---- hidden layers: A/bias register-prefetched one layer ahead ----
    #pragma unroll
    for (int L = 0; L < NLAYER; ++L){
      const unsigned char* br = sH[L & 1] + m0*128;
      unsigned char* bw = sH[(L+1) & 1];

      int8v b00 = ld_b(br,        q, m0);   // g0, h
      int8v b01 = ld_b(br + 4096, q, m0);   // g0, d
      int8v b10 = ld_b(br + 2048, q, m0);   // g1, h
      int8v b11 = ld_b(br + 6144, q, m0);   // g1, d

      float4v acc[2][2][2];
      acc[0][0][0] = mfma128(pa0, b00);
      acc[0][0][1] = mfma128(pa0, b01);
      acc[0][1][0] = mfma128(pa0, b10);
      acc[0][1][1] = mfma128(pa0, b11);
      acc[1][0][0] = mfma128(pa1, b00);
      acc[1][0][1] = mfma128(pa1, b01);
      acc[1][1][0] = mfma128(pa1, b10);
      acc[1][1][1] = mfma128(pa1, b11);

      float2v bl0 = pbl0, bh0 = pbh0, bl1 = pbl1, bh1 = pbh1;

      // prefetch next layer's A/bias (loads fly during epilogue + barrier)
      if (L < NLAYER-1){
        const unsigned char* nimg = wimg + (size_t)(L+1)*IMGB;
        pa0 = ld_a(nimg + aoff0);
        pa1 = ld_a(nimg + aoff1);
        float4v tb0 = *(const float4v*)(bhp + (L+1)*128 + (2*w + 0)*16 + q*4);
        float4v tb1 = *(const float4v*)(bhp + (L+1)*128 + (2*w + 1)*16 + q*4);
        pbl0 = pk_mul(lo2(tb0), v256p); pbh0 = pk_mul(hi2(tb0), v256p);
        pbl1 = pk_mul(lo2(tb1), v256p); pbh1 = pk_mul(hi2(tb1), v256p);
      }

      // epilogue -> other buffer; u = acc0 + 256b, folded-scale u-polys
      const bool last = (L == NLAYER-1);
      #pragma unroll
      for (int t = 0; t < 2; ++t){
        const int I = 2*w + t;
        float2v bl = t ? bl1 : bl0;
        float2v bh = t ? bh1 : bh0;
        const int off = ((2*I + (q >> 1)) ^ m0) * 8 + (q & 1) * 4;
        #pragma unroll
        for (int gg = 0; gg < 2; ++gg){
          float2v ua = pk_add(lo2(acc[t][gg][0]), bl);
          float2v ub = pk_add(hi2(acc[t][gg][0]), bh);
          float2v u2a = pk_mul(ua, ua), u2b = pk_mul(ub, ub);
          float2v ga = pk_fma(ua, pk_fma(u2a, G3, G1), G0);
          float2v gb = pk_fma(ub, pk_fma(u2b, G3, G1), G0);
          float2v da = pk_mul(ga, lo2(acc[t][gg][1]));
          float2v db = pk_mul(gb, hi2(acc[t][gg][1]));
          unsigned char* base = bw + (gg*16 + m0)*128;
          if (!last){
            float2v ha = pk_mul(ua, pk_fma(ua, pk_fma(u2a, K3, K1), K0));
            float2v hb = pk_mul(ub, pk_fma(ub, pk_fma(u2b, K3, K1), K0));
            *(unsigned*)(base + off) = pk4fp8(ha[0], ha[1], hb[0], hb[1]);
          }
          *(unsigned*)(base + 4096 + off) = pk4fp8(da[0], da[1], db[0], db[1]);
        }
      }
      __syncthreads();   // sH[(L+1)&1] ready for next layer's B reads
    }

    // ---- reduce: s_raw = S_d7 . Wo (= 262144 * s); S_d7 is in sH[1] ----
    {
      const unsigned char* pD = sH[1] + 4096 + r*128;
      float2v sv = {0.f, 0.f};
      #pragma unroll
      for (int c = 0; c < 2; ++c){
        u64 dv8 = *(const u64*)(pD + ((2*sg + c) ^ rs) * 8);
        unsigned wlo = (unsigned)dv8, whi = (unsigned)(dv8 >> 32);
        float4v woa = *(const float4v*)(Wop + sg*16 + c*8);
        float4v wob = *(const float4v*)(Wop + sg*16 + c*8 + 4);
        sv = pk_fma(up2<false>(wlo), lo2(woa), sv);
        sv = pk_fma(up2<true>(wlo),  hi2(woa), sv);
        sv = pk_fma(up2<false>(whi), lo2(wob), sv);
        sv = pk_fma(up2<true>(whi),  hi2(wob), sv);
      }
      float s = sv[0] + sv[1];
      s += __shfl_xor(s, 1);
      s += __shfl_xor(s, 2);
      s += __shfl_xor(s, 4);
      if (isT) qv = fmaf(coefs[ev], s, qv);
      else     pv = fmaf(coefs[ev], s, pv);
    }
    // no barrier needed: next L0 writes sH[0] (last read before this eval's
    // final barrier); reduce reads sH[1], next written only after next L0 barrier.
  }

  if (sg == 0){
    out[(e0 + r)*4 + col]     = qv;
    out[(e0 + r)*4 + 2 + col] = pv;
  }
}

extern "C" void kernel_launch(void* const* d_in, const int* in_sizes, int n_in,
                              void* d_out, int out_size, void* d_ws, size_t ws_size,
                              hipStream_t stream)
{
  const float* X   = (const float*)d_in[0];
  const float* lW0 = (const float*)d_in[1];
  const float* lb0 = (const float*)d_in[2];
  const float* lWh = (const float*)d_in[3];
  const float* lbh = (const float*)d_in[4];
  const float* lWo = (const float*)d_in[5];
  const float* rW0 = (const float*)d_in[7];
  const float* rb0 = (const float*)d_in[8];
  const float* rWh = (const float*)d_in[9];
  const float* rbh = (const float*)d_in[10];
  const float* rWo = (const float*)d_in[11];
  const int*   li  = (const int*)d_in[13];
  const int*   ri  = (const int*)d_in[14];
  unsigned char* wbf = (unsigned char*)d_ws;   // 4*7*16384 B = 458752 B
  float* out = (float*)d_out;
  const int B = in_sizes[0] / 4;

  hipLaunchKernelGGL(prep_weights, dim3(4*NLAYER), dim3(256), 0, stream,
                     lWh, rWh, wbf);
  hipLaunchKernelGGL(sympl_main, dim3(B/32, 2), dim3(256), 0, stream,
                     X, lW0, lb0, lbh, lWo, rW0, rb0, rbh, rWo, li, ri, wbf, out);
}

// Round 11
// 206.780 us; speedup vs baseline: 1.0396x; 1.0396x over previous
//
#include <hip/hip_runtime.h>

#define NLAYER 7
#define IMGB 16384          // bytes per weight-layer image: A[n][k] fp8, plain row-major
#define WSCALE 16.0f        // weights stored x16 (e4m3 subnormal protection)

typedef __attribute__((ext_vector_type(2))) float float2v;
typedef __attribute__((ext_vector_type(4))) float float4v;
typedef __attribute__((ext_vector_type(2))) int   int2v;
typedef __attribute__((ext_vector_type(4))) int   int4v;
typedef __attribute__((ext_vector_type(4))) unsigned int uint4v;
typedef __attribute__((ext_vector_type(8))) int   int8v;
typedef unsigned long long u64;

__device__ __forceinline__ float2v f2fma(float2v a, float2v b, float2v c){
  return __builtin_elementwise_fma(a, b, c);
}
__device__ __forceinline__ float2v lo2(float4v v){ return (float2v){v[0], v[1]}; }
__device__ __forceinline__ float2v hi2(float4v v){ return (float2v){v[2], v[3]}; }

// pack 4 f32 -> 4 fp8 e4m3 bytes (ascending)
__device__ __forceinline__ unsigned pk4fp8(float v0, float v1, float v2, float v3){
  int w = __builtin_amdgcn_cvt_pk_fp8_f32(v0, v1, 0, false);
  w = __builtin_amdgcn_cvt_pk_fp8_f32(v2, v3, w, true);
  return (unsigned)w;
}
template<bool HI>
__device__ __forceinline__ float2v up2(unsigned w){
  return __builtin_amdgcn_cvt_pk_f32_fp8((int)w, HI);
}
// MX-scaled MFMA, K=128, fp8 e4m3 both operands, unit scales
__device__ __forceinline__ float4v mfma128(int8v a, int8v b){
  return __builtin_amdgcn_mfma_scale_f32_16x16x128_f8f6f4(
      a, b, (float4v){0.f,0.f,0.f,0.f}, 0, 0, 0, 0x7F7F7F7F, 0, 0x7F7F7F7F);
}
// P16 = 16*Phi(z) (cubic Taylor), gp16 = 16*gelu'(z)  [natural z scale, L0 only]
__device__ __forceinline__ void act2(float2v z, float2v& P16, float2v& gp16){
  const float2v c1v  = {6.3830764862829235f, 6.3830764862829235f};
  const float2v c3v  = {-1.0638460810704874f, -1.0638460810704874f};
  const float2v c33v = {-3.1915382432114624f, -3.1915382432114624f};
  const float2v v8   = {8.f, 8.f};
  float2v z2 = z * z;
  float2v u  = f2fma(z2, c3v, c1v);
  P16 = f2fma(z, u, v8);
  float2v Pd = f2fma(z2, c33v, c1v);
  gp16 = f2fma(z, Pd, P16);
}

// B gather: 4 b64 reads at pinned per-lane vaddrs + compile-time imm
__device__ __forceinline__ int8v ld_b(const unsigned char* r0, const unsigned char* r1,
                                      const unsigned char* r2, const unsigned char* r3,
                                      int imm){
  int2v x0 = *(const int2v*)(r0 + imm);
  int2v x1 = *(const int2v*)(r1 + imm);
  int2v x2 = *(const int2v*)(r2 + imm);
  int2v x3 = *(const int2v*)(r3 + imm);
  int4v lo = __builtin_shufflevector(x0, x1, 0, 1, 2, 3);
  int4v hi = __builtin_shufflevector(x2, x3, 0, 1, 2, 3);
  return __builtin_shufflevector(lo, hi, 0, 1, 2, 3, 4, 5, 6, 7);
}
// A operand: 32 contiguous bytes from global (2x dwordx4)
__device__ __forceinline__ int8v ld_a(const unsigned char* p){
  int4v a0 = *(const int4v*)(p);
  int4v a1 = *(const int4v*)(p + 16);
  return __builtin_shufflevector(a0, a1, 0, 1, 2, 3, 4, 5, 6, 7);
}

// ---- prep: Wh fp32 [side][term][L][k][n] -> fp8 image [net][L][n][k] (plain), W*16 ----
__global__ __launch_bounds__(256)
void prep_weights(const float* __restrict__ lWh,
                  const float* __restrict__ rWh,
                  unsigned char* __restrict__ wbf)
{
  __shared__ __align__(16) unsigned char T[IMGB];
  const int b = blockIdx.x;               // net*7 + L
  const int net = b / NLAYER, L = b % NLAYER;
  const int side = net >> 1, term = net & 1;
  const float* src = (side ? rWh : lWh) + (size_t)((term*NLAYER + L)*128)*128;
  const int t = threadIdx.x;
  {
    const int k = t >> 1, n0 = (t & 1)*64;
    const float* row = src + k*128 + n0;
    #pragma unroll
    for (int c4 = 0; c4 < 4; ++c4){
      float4v f0 = *(const float4v*)(row + c4*16);
      float4v f1 = *(const float4v*)(row + c4*16 + 4);
      float4v f2 = *(const float4v*)(row + c4*16 + 8);
      float4v f3 = *(const float4v*)(row + c4*16 + 12);
      uint4v wv = { pk4fp8(f0[0]*WSCALE, f0[1]*WSCALE, f0[2]*WSCALE, f0[3]*WSCALE),
                    pk4fp8(f1[0]*WSCALE, f1[1]*WSCALE, f1[2]*WSCALE, f1[3]*WSCALE),
                    pk4fp8(f2[0]*WSCALE, f2[1]*WSCALE, f2[2]*WSCALE, f2[3]*WSCALE),
                    pk4fp8(f3[0]*WSCALE, f3[1]*WSCALE, f3[2]*WSCALE, f3[3]*WSCALE) };
      *(uint4v*)&T[k*128 + n0 + c4*16] = wv;
    }
  }
  __syncthreads();
  {
    const int n = t >> 1, c0 = (t & 1)*8;
    unsigned char* dst = wbf + ((size_t)b << 14) + n*128;
    #pragma unroll
    for (int c = 0; c < 8; ++c){
      const int kc = (c0 + c)*8;
      u64 v = 0;
      #pragma unroll
      for (int j = 0; j < 8; ++j)
        v |= (u64)T[(kc + j)*128 + n] << (8*j);
      *(u64*)(dst + (c0 + c)*8) = v;
    }
  }
}

__global__ __launch_bounds__(256, 4)
void sympl_main(const float* __restrict__ X,
                const float* __restrict__ lW0, const float* __restrict__ lb0,
                const float* __restrict__ lbh, const float* __restrict__ lWo,
                const float* __restrict__ rW0, const float* __restrict__ rb0,
                const float* __restrict__ rbh, const float* __restrict__ rWo,
                const int* __restrict__ lidx, const int* __restrict__ ridx,
                const unsigned char* __restrict__ wbf,
                float* __restrict__ out)
{
  // two 16-element tiles, each double-buffered:
  // addr = tile*8192 + buf*4096 + stream*2048 + row*128 + swizzled-chunk*8
  // (chunk c of row e lives at ((c ^ (e&15))*8)
  __shared__ __align__(16) unsigned char sH[16384];

  const int tid  = threadIdx.x;
  const int lane = tid & 63;
  const int w    = tid >> 6;
  const int m0   = lane & 15;
  const int q    = lane >> 4;
  const int col  = blockIdx.y;
  const int e0   = blockIdx.x * 32;
  const int r    = tid >> 3;       // element 0..31 (8 threads each)
  const int sg   = tid & 7;
  const int rs   = r & 15;

  const int lt = (lidx[0] == col) ? 0 : 1;
  const int rt = (ridx[0] == col) ? 0 : 1;

  float qv = X[(e0 + r)*4 + col];
  float pv = X[(e0 + r)*4 + 2 + col];

  const float dt = 0.1f;
  const float C0 = 0.6756035959798289f, C1 = -0.17560359597982883f;
  const float D0 = 1.3512071919596578f, D1 = -1.7024143839193153f;
  const float is = 1.0f / 262144.0f;   // unwind final S_d scale 16*4^7
  const float coefs[7] = { C0*dt*is, -D0*dt*is, C1*dt*is, -D1*dt*is,
                           C1*dt*is, -D0*dt*is, C0*dt*is };

  // u-domain epilogue constants (u = 256*z), R5/R10-verified folded scales
  const float2v K0 = {0.03125f, 0.03125f};
  const float2v K1 = {9.739801768e-5f, 9.739801768e-5f};
  const float2v K3 = {-2.476767495e-10f, -2.476767495e-10f};
  const float2v G0 = {0.125f, 0.125f};
  const float2v G1 = {7.791841414e-4f, 7.791841414e-4f};
  const float2v G3 = {-3.962875977e-9f, -3.962875977e-9f};
  const float2v v256p = {256.f, 256.f};

  // pinned per-lane LDS addresses (all later accesses use compile-time imm)
  const unsigned char* rp0 = sH + m0*128 + (((4*q+0) ^ m0)*8);
  const unsigned char* rp1 = sH + m0*128 + (((4*q+1) ^ m0)*8);
  const unsigned char* rp2 = sH + m0*128 + (((4*q+2) ^ m0)*8);
  const unsigned char* rp3 = sH + m0*128 + (((4*q+3) ^ m0)*8);
  unsigned char* wp0 = sH + m0*128 + (((2*(2*w+0) + (q>>1)) ^ m0)*8) + (q&1)*4;
  unsigned char* wp1 = sH + m0*128 + (((2*(2*w+1) + (q>>1)) ^ m0)*8) + (q&1)*4;
  unsigned char* l0w0 = sH + (r>>4)*8192 + rs*128 + (((2*sg+0) ^ rs)*8);
  unsigned char* l0w1 = sH + (r>>4)*8192 + rs*128 + (((2*sg+1) ^ rs)*8);

  // per-wave global A offsets (I-tiles 2w, 2w+1)
  const int aoff0 = ((2*w + 0)*16 + m0)*128 + q*32;
  const int aoff1 = ((2*w + 1)*16 + m0)*128 + q*32;

  int8v   pa0, pa1;                       // prefetched A-frags (shared by both tiles)
  float2v pbl0, pbh0, pbl1, pbh1;         // prefetched prescaled biases (256*b)

#define MFMA_TILE(a00,a01,a10,a11, IMM) { \
    int8v bh_ = ld_b(rp0,rp1,rp2,rp3, (IMM)); \
    int8v bd_ = ld_b(rp0,rp1,rp2,rp3, (IMM)+2048); \
    a00 = mfma128(pa0, bh_); a01 = mfma128(pa0, bd_); \
    a10 = mfma128(pa1, bh_); a11 = mfma128(pa1, bd_); }

#define EPI_HALF(aH,aD, BL,BH, WP, WIMM, LASTF) { \
    float2v ua = lo2(aH) + (BL), ub = hi2(aH) + (BH); \
    float2v u2a = ua*ua, u2b = ub*ub; \
    float2v ga = f2fma(ua, f2fma(u2a, G3, G1), G0); \
    float2v gb = f2fma(ub, f2fma(u2b, G3, G1), G0); \
    float2v da = ga * lo2(aD), db = gb * hi2(aD); \
    if (!(LASTF)){ \
      float2v ha = ua * f2fma(ua, f2fma(u2a, K3, K1), K0); \
      float2v hb = ub * f2fma(ub, f2fma(u2b, K3, K1), K0); \
      *(unsigned*)((WP) + (WIMM)) = pk4fp8(ha[0], ha[1], hb[0], hb[1]); } \
    *(unsigned*)((WP) + (WIMM) + 2048) = pk4fp8(da[0], da[1], db[0], db[1]); }

#define EPI_TILE(a00,a01,a10,a11, WIMM, LASTF) { \
    EPI_HALF(a00, a01, cbl0, cbh0, wp0, (WIMM), (LASTF)); \
    EPI_HALF(a10, a11, cbl1, cbh1, wp1, (WIMM), (LASTF)); }

  for (int ev = 0; ev < 7; ++ev){
    const bool isT = !(ev & 1);
    const int  term = isT ? rt : lt;
    const float* W0p = (isT ? rW0 : lW0) + term*128;
    const float* b0p = (isT ? rb0 : lb0) + term*128;
    const float* bhp = (isT ? rbh : lbh) + term*NLAYER*128;
    const float* Wop = (isT ? rWo : lWo) + term*128;
    const unsigned char* wimg = wbf + (size_t)(((isT ? 2 : 0) + term)*NLAYER)*IMGB;

    // prefetch L=0 operands (hidden by layer-0 compute + barrier)
    pa0 = ld_a(wimg + aoff0);
    pa1 = ld_a(wimg + aoff1);
    {
      float4v tb0 = *(const float4v*)(bhp + (2*w + 0)*16 + q*4);
      float4v tb1 = *(const float4v*)(bhp + (2*w + 1)*16 + q*4);
      pbl0 = lo2(tb0)*v256p; pbh0 = hi2(tb0)*v256p;
      pbl1 = lo2(tb1)*v256p; pbh1 = hi2(tb1)*v256p;
    }

    // ---- layer 0 -> both tiles' buf0 ----
    {
      const float x = isT ? pv : qv;
      const float2v xv = {x, x};
      #pragma unroll
      for (int c = 0; c < 2; ++c){
        int n0 = sg*16 + c*8;
        float4v wa = *(const float4v*)(W0p + n0);
        float4v wb = *(const float4v*)(W0p + n0 + 4);
        float4v ba = *(const float4v*)(b0p + n0);
        float4v bb = *(const float4v*)(b0p + n0 + 4);
        float2v zp[4] = { f2fma(xv, lo2(wa), lo2(ba)), f2fma(xv, hi2(wa), hi2(ba)),
                          f2fma(xv, lo2(wb), lo2(bb)), f2fma(xv, hi2(wb), hi2(bb)) };
        float2v wpk[4] = { lo2(wa), hi2(wa), lo2(wb), hi2(wb) };
        float Sh[8], Sd[8];
        #pragma unroll
        for (int pp = 0; pp < 4; ++pp){
          float2v P16, gp16; act2(zp[pp], P16, gp16);
          float2v h = zp[pp] * P16;
          float2v d = gp16 * wpk[pp];
          Sh[pp*2] = h[0]; Sh[pp*2+1] = h[1];
          Sd[pp*2] = d[0]; Sd[pp*2+1] = d[1];
        }
        unsigned char* l0w = c ? l0w1 : l0w0;
        *(unsigned*)(l0w)          = pk4fp8(Sh[0],Sh[1],Sh[2],Sh[3]);
        *(unsigned*)(l0w + 4)      = pk4fp8(Sh[4],Sh[5],Sh[6],Sh[7]);
        *(unsigned*)(l0w + 2048)   = pk4fp8(Sd[0],Sd[1],Sd[2],Sd[3]);
        *(unsigned*)(l0w + 2052)   = pk4fp8(Sd[4],Sd[5],Sd[6],Sd[7]);
      }
    }
    __syncthreads();

    float4v aA00, aA01, aA10, aA11;
    float4v aB00, aB01, aB10, aB11;
    float2v cbl0, cbh0, cbl1, cbh1;

    // mfmaA(0): tile A, buf0
    MFMA_TILE(aA00, aA01, aA10, aA11, 0);

    #pragma unroll
    for (int L = 0; L < NLAYER; ++L){
      const int cb_ = (L & 1) * 4096;
      const int nb  = ((L+1) & 1) * 4096;
      const bool last = (L == NLAYER-1);

      cbl0 = pbl0; cbh0 = pbh0; cbl1 = pbl1; cbh1 = pbh1;   // layer-L biases

      // phase 1: epilogue(A,L) + mfma(B,L) + prefetch(L+1)
      EPI_TILE(aA00, aA01, aA10, aA11, nb, last);
      MFMA_TILE(aB00, aB01, aB10, aB11, 8192 + cb_);
      if (L < NLAYER-1){
        const unsigned char* nimg = wimg + (size_t)(L+1)*IMGB;
        pa0 = ld_a(nimg + aoff0);
        pa1 = ld_a(nimg + aoff1);
        float4v tb0 = *(const float4v*)(bhp + (L+1)*128 + (2*w + 0)*16 + q*4);
        float4v tb1 = *(const float4v*)(bhp + (L+1)*128 + (2*w + 1)*16 + q*4);
        pbl0 = lo2(tb0)*v256p; pbh0 = hi2(tb0)*v256p;
        pbl1 = lo2(tb1)*v256p; pbh1 = hi2(tb1)*v256p;
      }
      __syncthreads();

      // phase 2: epilogue(B,L) + mfma(A,L+1)
      EPI_TILE(aB00, aB01, aB10, aB11, 8192 + nb, last);
      if (L < NLAYER-1){
        MFMA_TILE(aA00, aA01, aA10, aA11, nb);
      }
      __syncthreads();
    }

    // ---- reduce: s_raw = S_d7 . Wo (= 262144*s); d-stream of buf1, own tile ----
    {
      float2v sv = {0.f, 0.f};
      #pragma unroll
      for (int c = 0; c < 2; ++c){
        const unsigned char* l0w = c ? l0w1 : l0w0;
        u64 dv8 = *(const u64*)(l0w + 4096 + 2048);
        unsigned wlo = (unsigned)dv8, whi = (unsigned)(dv8 >> 32);
        float4v woa = *(const float4v*)(Wop + sg*16 + c*8);
        float4v wob = *(const float4v*)(Wop + sg*16 + c*8 + 4);
        sv = f2fma(up2<false>(wlo), lo2(woa), sv);
        sv = f2fma(up2<true>(wlo),  hi2(woa), sv);
        sv = f2fma(up2<false>(whi), lo2(wob), sv);
        sv = f2fma(up2<true>(whi),  hi2(wob), sv);
      }
      float s = sv[0] + sv[1];
      s += __shfl_xor(s, 1);
      s += __shfl_xor(s, 2);
      s += __shfl_xor(s, 4);
      if (isT) qv = fmaf(coefs[ev], s, qv);
      else     pv = fmaf(coefs[ev], s, pv);
    }
    // no barrier: next L0 writes buf0 (last read 2 barriers ago); reduce reads
    // buf1-d, next overwritten only after the next post-L0 barrier.
  }

  if (sg == 0){
    out[(e0 + r)*4 + col]     = qv;
    out[(e0 + r)*4 + 2 + col] = pv;
  }
#undef MFMA_TILE
#undef EPI_HALF
#undef EPI_TILE
}

extern "C" void kernel_launch(void* const* d_in, const int* in_sizes, int n_in,
                              void* d_out, int out_size, void* d_ws, size_t ws_size,
                              hipStream_t stream)
{
  const float* X   = (const float*)d_in[0];
  const float* lW0 = (const float*)d_in[1];
  const float* lb0 = (const float*)d_in[2];
  const float* lWh = (const float*)d_in[3];
  const float* lbh = (const float*)d_in[4];
  const float* lWo = (const float*)d_in[5];
  const float* rW0 = (const float*)d_in[7];
  const float* rb0 = (const float*)d_in[8];
  const float* rWh = (const float*)d_in[9];
  const float* rbh = (const float*)d_in[10];
  const float* rWo = (const float*)d_in[11];
  const int*   li  = (const int*)d_in[13];
  const int*   ri  = (const int*)d_in[14];
  unsigned char* wbf = (unsigned char*)d_ws;   // 4*7*16384 B = 458752 B
  float* out = (float*)d_out;
  const int B = in_sizes[0] / 4;

  hipLaunchKernelGGL(prep_weights, dim3(4*NLAYER), dim3(256), 0, stream,
                     lWh, rWh, wbf);
  hipLaunchKernelGGL(sympl_main, dim3(B/32, 2), dim3(256), 0, stream,
                     X, lW0, lb0, lbh, lWo, rW0, rb0, rbh, rWo, li, ri, wbf, out);
}